// Round 16
// baseline (511.916 us; speedup 1.0000x reference)
//
#include <hip/hip_runtime.h>
#include <hip/hip_bf16.h>
#include <math.h>

#define BB 8
#define NN 128
#define HH 128
#define NHD 4
#define DHD 32
#define LAY 4
#define EPSV 1e-5f

typedef __hip_bfloat16 bf16;
typedef unsigned short ushortt;
typedef short bf16x8 __attribute__((ext_vector_type(8)));
typedef float f32x4 __attribute__((ext_vector_type(4)));

__device__ __forceinline__ float b2f(bf16 x){ return __bfloat162float(x); }
__device__ __forceinline__ bf16 f2b(float x){ return __float2bfloat16(x); }
__device__ __forceinline__ float us2f(ushortt u){ return __uint_as_float(((unsigned)u)<<16); }
__device__ __forceinline__ ushortt f2us(float x){ bf16 b=__float2bfloat16(x); return *(ushortt*)&b; }
__device__ __forceinline__ float gelu_f(float x){ return 0.5f*x*(1.0f+erff(x*0.7071067811865476f)); }
// fast tanh-gelu — h-path (G precompute); r13-verified on this path
__device__ __forceinline__ float gelu_h(float x){
  float t = 0.7978845608028654f*x*(1.0f + 0.044715f*x*x);
  float e = __expf(2.0f*t);
  float th = 1.0f - 2.0f/(e + 1.0f);
  return 0.5f*x*(1.0f + th);
}

// ---------------- prep: bf16 weights, transposes, bondW (all layers), xf init ----------------

__global__ __launch_bounds__(256) void k_prep(const float* __restrict__ fe2W,
    const float* __restrict__ preW, const float* __restrict__ eigW,
    const float* __restrict__ qkvW, const float* __restrict__ outW,
    const float* __restrict__ ffn1W, const float* __restrict__ ffn2W,
    const float* __restrict__ f1W, const float* __restrict__ f2W,
    const float* __restrict__ aemb, const int* __restrict__ nf,
    const float* __restrict__ bemb, const float* __restrict__ preb,
    ushortt* __restrict__ wbf, float* __restrict__ gs, float* __restrict__ xf0,
    float* __restrict__ eigWT, float* __restrict__ qkvWT, float* __restrict__ outWT,
    float* __restrict__ ffn1WT, float* __restrict__ ffn2WT,
    float* __restrict__ f1WT, float* __restrict__ f2WT,
    float* __restrict__ bondWall){
  int idx = blockIdx.x*256 + threadIdx.x;    // grid covers 131072
  if (idx < 2048) gs[idx] = 0.f;
  if (idx < 81920){
    float v = (idx < 16384) ? fe2W[idx] : preW[idx - 16384];
    wbf[idx] = f2us(v);
  }
  if (idx < 131072){
    int node = idx >> 7, h2 = idx & 127;
    xf0[idx] = aemb[nf[node]*HH + h2];
  }
  if (idx < 16512){ int o = idx/129, kq = idx - o*129; eigWT[kq*128+o] = eigW[idx]; }
  if (idx < 49152){ int o = idx>>7, m = idx&127; qkvWT[m*384+o] = qkvW[idx]; }
  if (idx < 16384){ int o = idx>>7, m = idx&127;
    outWT[m*128+o]  = outW[idx];
    ffn1WT[m*128+o] = ffn1W[idx];
    ffn2WT[m*128+o] = ffn2W[idx];
  }
  if (idx < 65536){ int l = idx>>14, r = idx&16383; int o = r>>7, m = r&127;
    f1WT[l*16384 + m*128+o] = f1W[idx];
    f2WT[l*16384 + m*128+o] = f2W[idx];
  }
  if (idx < 5120){   // bondW for all 4 layers: bond_emb @ preW[l]^T + preb[l]
    int l = idx / 1280; int r = idx - l*1280; int e2 = r >> 7; int hcol = r & 127;
    const float* br = bemb + e2*128;
    const float* wr = preW + l*16384 + hcol*128;
    float acc = preb[l*128 + hcol];
    for (int m=0;m<128;m++) acc += br[m]*wr[m];
    bondWall[idx] = acc;
  }
}

// ---------------- front end (all f32 — precision-critical for new_e) ----------------

__global__ void k_fe_a(const float* __restrict__ e, const float* __restrict__ eigWT,
                       const float* __restrict__ eigb, const float* __restrict__ g,
                       const float* __restrict__ bt, const float* __restrict__ qkvWT,
                       const float* __restrict__ qkvb,
                       float* __restrict__ eigout, float* __restrict__ q,
                       float* __restrict__ kT, float* __restrict__ v){
  int row = blockIdx.x; int tid = threadIdx.x;
  int b = row >> 7, n = row & 127;
  __shared__ float ee[129]; __shared__ float buf[128]; __shared__ float xm[128];
  float ev = e[row];
  if (tid < 64){
    float dv = expf(-0.1439115683121279f * (float)tid);
    float pe = ev * 100.0f * dv;
    ee[1+tid] = sinf(pe);
    ee[65+tid] = cosf(pe);
  }
  if (tid == 0) ee[0] = ev;
  __syncthreads();
  float x = eigb[tid];
  for (int k2=0;k2<129;k2++) x += ee[k2]*eigWT[k2*128+tid];
  eigout[row*HH+tid] = x;
  buf[tid]=x; __syncthreads();
  for (int s2=64;s2>0;s2>>=1){ if(tid<s2) buf[tid]+=buf[tid+s2]; __syncthreads(); }
  float mean = buf[0]*(1.0f/128.0f); __syncthreads();
  float d = x-mean; buf[tid]=d*d; __syncthreads();
  for (int s2=64;s2>0;s2>>=1){ if(tid<s2) buf[tid]+=buf[tid+s2]; __syncthreads(); }
  float var = buf[0]*(1.0f/128.0f);
  xm[tid] = d*rsqrtf(var+EPSV)*g[tid]+bt[tid];
  __syncthreads();
  #pragma unroll
  for (int s3=0;s3<3;s3++){
    float acc = qkvb[s3*HH+tid];
    const float* wt = qkvWT + s3*HH + tid;
    for (int m=0;m<HH;m++) acc += xm[m]*wt[m*384];
    if (s3==0) q[row*HH+tid]=acc;
    else if (s3==1) kT[b*16384 + tid*128 + n]=acc;
    else v[row*HH+tid]=acc;
  }
}

__global__ void k_attn(const float* __restrict__ q, const float* __restrict__ kT,
                       const int* __restrict__ length,
                       float* __restrict__ attnf, float* __restrict__ outp){
  int bx = blockIdx.x;
  int qi = bx & 127, hd = (bx>>7)&3, b = bx>>9;
  int tid = threadIdx.x;
  int len = length[b];
  __shared__ float qv[DHD]; __shared__ float red[128];
  if (tid < DHD) qv[tid] = q[(b*NN+qi)*HH + hd*DHD + tid];
  __syncthreads();
  float s = -1e30f;
  if (tid < len){
    const float* kr = kT + b*16384 + hd*DHD*128 + tid;
    float sc=0.f;
    for (int d2=0; d2<DHD; d2++) sc += qv[d2]*kr[d2*128];
    s = sc * 0.17677669529663687f;
  }
  red[tid]=s; __syncthreads();
  for (int st=64;st>0;st>>=1){ if(tid<st) red[tid]=fmaxf(red[tid],red[tid+st]); __syncthreads(); }
  float mx = red[0]; __syncthreads();
  float p = (tid<len)? expf(s-mx):0.0f;
  red[tid]=p; __syncthreads();
  for (int st=64;st>0;st>>=1){ if(tid<st) red[tid]+=red[tid+st]; __syncthreads(); }
  float a = p / red[0];
  int idx = ((b*NHD+hd)*NN+qi)*NN+tid;
  attnf[idx]=a;
  outp[4104 + idx]=a;
}

__global__ void k_fe_c(const float* __restrict__ attnf, const float* __restrict__ v,
                       const float* __restrict__ outWT, const float* __restrict__ outb,
                       const float* __restrict__ fng, const float* __restrict__ fnb,
                       const float* __restrict__ w1T, const float* __restrict__ b1,
                       const float* __restrict__ w2T, const float* __restrict__ b2,
                       float* __restrict__ eig){
  int row = blockIdx.x; int b = row>>7, qi = row&127;
  int tid = threadIdx.x;
  __shared__ float c[128]; __shared__ float buf[128]; __shared__ float xm[128]; __shared__ float tt[128];
  int hd = tid>>5;
  const float* ar = attnf + ((b*NHD+hd)*NN+qi)*NN;
  float acc=0.f;
  for (int j=0;j<NN;j++) acc += ar[j]*v[(b*NN+j)*HH+tid];
  c[tid]=acc; __syncthreads();
  float o = outb[tid];
  for (int m=0;m<HH;m++) o += c[m]*outWT[m*128+tid];
  float x = eig[row*HH+tid] + o;
  buf[tid]=x; __syncthreads();
  for (int s2=64;s2>0;s2>>=1){ if(tid<s2) buf[tid]+=buf[tid+s2]; __syncthreads(); }
  float mean=buf[0]*(1.f/128.f); __syncthreads();
  float d=x-mean; buf[tid]=d*d; __syncthreads();
  for (int s2=64;s2>0;s2>>=1){ if(tid<s2) buf[tid]+=buf[tid+s2]; __syncthreads(); }
  float var=buf[0]*(1.f/128.f);
  xm[tid]=d*rsqrtf(var+EPSV)*fng[tid]+fnb[tid];
  __syncthreads();
  float a1=b1[tid];
  for (int m=0;m<HH;m++) a1+=xm[m]*w1T[m*128+tid];
  tt[tid]=gelu_f(a1); __syncthreads();
  float a2=b2[tid];
  for (int m=0;m<HH;m++) a2+=tt[m]*w2T[m*128+tid];
  eig[row*HH+tid]=x+a2;
}

__global__ void k_dec(const float* __restrict__ eig, const float* dW, const float* db,
                      float* __restrict__ newe, float* __restrict__ outp){
  int b = blockIdx.x, n = threadIdx.x;
  __shared__ float w[NHD*HH];
  for (int i=n;i<NHD*HH;i+=128) w[i]=dW[i];
  __syncthreads();
  float acc[NHD];
  #pragma unroll
  for (int kk=0;kk<NHD;kk++) acc[kk]=db[kk];
  const float* er = eig + (b*NN+n)*HH;
  for (int h2=0;h2<HH;h2++){
    float ev = er[h2];
    #pragma unroll
    for (int kk=0;kk<NHD;kk++) acc[kk]+=ev*w[kk*HH+h2];
  }
  #pragma unroll
  for (int kk=0;kk<NHD;kk++){
    int idx=(b*NHD+kk)*NN+n; newe[idx]=acc[kk];
    outp[8 + idx]=acc[kk];
  }
}

// ---------------- bases ----------------

__global__ void k_filters(const float* __restrict__ u, const float* __restrict__ newe,
                          float* __restrict__ filt){
  int b = blockIdx.x, n0 = blockIdx.y*16, p0 = blockIdx.z*16;
  int tx = threadIdx.x, ty = threadIdx.y; int tid = ty*16+tx;
  __shared__ float un[16][17], upt[16][17], wk[4][16];
  float acc[4]={0.f,0.f,0.f,0.f};
  for (int mt=0; mt<8; mt++){
    __syncthreads();
    un[ty][tx]  = u[(b*NN+n0+ty)*NN + mt*16+tx];
    upt[tx][ty] = u[(b*NN+p0+ty)*NN + mt*16+tx];
    if (tid<64) wk[tid>>4][tid&15] = newe[(b*NHD+(tid>>4))*NN + mt*16 + (tid&15)];
    __syncthreads();
    #pragma unroll
    for (int mm=0;mm<16;mm++){
      float pr = un[ty][mm]*upt[mm][tx];
      #pragma unroll
      for (int kk=0;kk<4;kk++) acc[kk] += pr*wk[kk][mm];
    }
  }
  float4 o; o.x=acc[0];o.y=acc[1];o.z=acc[2];o.w=acc[3];
  *(float4*)&filt[((b*NN+n0+ty)*NN+p0+tx)*4] = o;
}

// bases: 2048 blocks (64 output rows each); exact gelu; coalesced stores
__global__ __launch_bounds__(256) void k_fe2(const float* __restrict__ filt,
    const float* __restrict__ w1g, const float* __restrict__ b1g,
    const ushortt* __restrict__ w2bf, const float* __restrict__ b2g,
    bf16* __restrict__ bases){
  int blk = blockIdx.x;
  int bi = blk >> 1;            // b*128 + n
  int r0 = (blk & 1)*64;
  int nloc = bi & 127;
  int tid = threadIdx.x;
  int lane = tid & 63, w = tid >> 6, quad = lane >> 4, l15 = lane & 15;
  __shared__ alignas(16) ushortt sT[64*132];
  __shared__ float w1[640], b1s[128], b2s[128];
  for (int i = tid; i < 640; i += 256) w1[i] = w1g[i];
  if (tid < 128){ b1s[tid] = b1g[tid]; b2s[tid] = b2g[tid]; }
  __syncthreads();
  int pr = r0 + w*16 + l15;
  float4 f4 = ((const float4*)filt)[bi*128 + pr];
  float dg = (pr == nloc) ? 1.0f : 0.0f;
  f32x4 acc[8];
  #pragma unroll
  for (int nt=0;nt<8;nt++) acc[nt] = (f32x4){0.f,0.f,0.f,0.f};
  for (int kk = 0; kk < 128; kk += 32){
    bf16x8 af;
    #pragma unroll
    for (int j=0;j<8;j++){
      int m = kk + quad*8 + j;
      float a = b1s[m] + w1[m*5]*dg + w1[m*5+1]*f4.x + w1[m*5+2]*f4.y
              + w1[m*5+3]*f4.z + w1[m*5+4]*f4.w;
      af[j] = (short)f2us(gelu_f(a));
    }
    #pragma unroll
    for (int nt=0;nt<8;nt++){
      bf16x8 bfr = *(const bf16x8*)&w2bf[(nt*16+l15)*128 + kk + quad*8];
      acc[nt] = __builtin_amdgcn_mfma_f32_16x16x32_bf16(af, bfr, acc[nt], 0, 0, 0);
    }
  }
  #pragma unroll
  for (int nt=0;nt<8;nt++){
    int h = nt*16 + l15;
    float bb = b2s[h];
    #pragma unroll
    for (int reg=0;reg<4;reg++){
      int lr = w*16 + quad*4 + reg;
      sT[lr*132 + h] = f2us(gelu_f(acc[nt][reg] + bb));
    }
  }
  __syncthreads();
  ushort4* gout = (ushort4*)(bases + (size_t)bi*16384 + r0*128);
  for (int idx = tid; idx < 2048; idx += 256){
    int row = idx >> 5, seg = idx & 31;
    gout[idx] = *(const ushort4*)&sT[row*132 + seg*4];
  }
}

// ---------------- message passing ----------------

// per-layer (8 blocks): fused BN2-apply of previous layer; xfW = xfB @ preW^T (MFMA)
__global__ __launch_bounds__(256) void k_xwl2(const float* __restrict__ xfprev,
    const float* __restrict__ t2, const float* __restrict__ gsum2p,
    const float* __restrict__ gsq2p, const float* __restrict__ g2p,
    const float* __restrict__ bb2p, const int* __restrict__ length, int prevapply,
    const ushortt* __restrict__ wbfl, float* __restrict__ xfB,
    float* __restrict__ xfW){
  int b = blockIdx.x;
  int tid = threadIdx.x;
  int lane = tid & 63, w = tid >> 6, quad = lane >> 4, l15 = lane & 15;
  __shared__ alignas(16) ushortt sA[128*136];
  __shared__ float smu[128], sistd[128], sg[128], sbb[128];
  if (prevapply && tid < 128){
    float cnt = 0.f;
    for (int q2=0;q2<BB;q2++) cnt += (float)length[q2];
    float mu = gsum2p[tid]/cnt;
    float var = gsq2p[tid]/cnt - mu*mu;
    smu[tid]=mu; sistd[tid]=rsqrtf(fmaxf(var,0.0f)+EPSV);
    sg[tid]=g2p[tid]; sbb[tid]=bb2p[tid];
  }
  __syncthreads();
  for (int idx = tid; idx < 4096; idx += 256){
    int r = idx >> 5, c = idx & 31;
    float4 xv = ((const float4*)xfprev)[(b*128 + r)*32 + c];
    if (prevapply){
      float4 tv = ((const float4*)t2)[(b*128 + r)*32 + c];
      int f0 = c*4;
      xv.x += fmaxf((tv.x-smu[f0+0])*sistd[f0+0]*sg[f0+0]+sbb[f0+0], 0.f);
      xv.y += fmaxf((tv.y-smu[f0+1])*sistd[f0+1]*sg[f0+1]+sbb[f0+1], 0.f);
      xv.z += fmaxf((tv.z-smu[f0+2])*sistd[f0+2]*sg[f0+2]+sbb[f0+2], 0.f);
      xv.w += fmaxf((tv.w-smu[f0+3])*sistd[f0+3]*sg[f0+3]+sbb[f0+3], 0.f);
      ((float4*)xfB)[(b*128 + r)*32 + c] = xv;
    }
    ushort4 o;
    o.x=f2us(xv.x); o.y=f2us(xv.y); o.z=f2us(xv.z); o.w=f2us(xv.w);
    *(ushort4*)&sA[r*136 + c*4] = o;
  }
  __syncthreads();
  f32x4 acc[2][8];
  #pragma unroll
  for (int mt=0;mt<2;mt++)
    #pragma unroll
    for (int nt=0;nt<8;nt++) acc[mt][nt] = (f32x4){0.f,0.f,0.f,0.f};
  #pragma unroll
  for (int kk = 0; kk < 128; kk += 32){
    bf16x8 af[2], bfr[8];
    #pragma unroll
    for (int mt=0;mt<2;mt++) af[mt] = *(const bf16x8*)&sA[(w*32+mt*16+l15)*136 + kk + quad*8];
    #pragma unroll
    for (int nt=0;nt<8;nt++) bfr[nt] = *(const bf16x8*)&wbfl[(nt*16+l15)*128 + kk + quad*8];
    #pragma unroll
    for (int mt=0;mt<2;mt++)
      #pragma unroll
      for (int nt=0;nt<8;nt++)
        acc[mt][nt] = __builtin_amdgcn_mfma_f32_16x16x32_bf16(af[mt], bfr[nt], acc[mt][nt], 0, 0, 0);
  }
  #pragma unroll
  for (int mt=0;mt<2;mt++)
    #pragma unroll
    for (int nt=0;nt<8;nt++){
      int h = nt*16 + l15;
      #pragma unroll
      for (int reg=0;reg<4;reg++){
        int pr = w*32 + mt*16 + quad*4 + reg;
        xfW[(b*128 + pr)*128 + h] = acc[mt][nt][reg];
      }
    }
}

// per-layer G precompute (1024 blocks): G[b][i][e][h] = gelu(xfW[i,h]+bondW[e,h]), bf16
// only 10 bond types -> 1.3M gelu instead of 16.7M in k_edge (12.8x reduction); 2.6MB, L2-resident
__global__ __launch_bounds__(256) void k_gel(const float* __restrict__ xfW,
    const float* __restrict__ bondWl, ushortt* __restrict__ G){
  int blk = blockIdx.x;                 // b*128 + i
  int tid = threadIdx.x;
  __shared__ float sx[128];
  if (tid < 128) sx[tid] = xfW[blk*128 + tid];
  __syncthreads();
  for (int idx = tid; idx < 1280; idx += 256){
    int h = idx & 127;
    G[(size_t)blk*1280 + idx] = f2us(gelu_h(sx[h] + bondWl[idx]));
  }
}

// per-edge (1024 blocks x 512 thr): pure gather-FMA using precomputed G; symmetric bases read
__global__ __launch_bounds__(512) void k_edge(const float* __restrict__ xfin, float* __restrict__ xfout,
    const bf16* __restrict__ bases, const ushortt* __restrict__ G,
    const int* __restrict__ ef, const int* __restrict__ length){
  int bj = blockIdx.x; int b = bj >> 7, j = bj & 127;
  int len = length[b];
  int tid = threadIdx.x; int h = tid & 127, ih = tid >> 7;   // ih in 0..3
  __shared__ int sEf[128];
  __shared__ float part[4][128];
  if (tid < 128) sEf[tid] = ef[(b*NN + tid)*NN + j];
  __syncthreads();
  float agg = 0.f;
  if (j < len){
    const ushortt* Gb = G + (size_t)(b*NN)*1280 + h;
    const bf16* bb = bases + ((size_t)b*NN + j)*NN*HH + h;
    for (int i = ih; i < len; i += 4){
      float vv = us2f(Gb[i*1280 + sEf[i]*128]);
      agg += vv * b2f(bb[i*128]);
    }
  }
  part[ih][h] = agg; __syncthreads();
  if (tid < 128){
    int o = (b*NN + j)*HH + tid;
    xfout[o] = xfin[o] + part[0][tid] + part[1][tid] + part[2][tid] + part[3][tid];
  }
}

// g1 GEMM (transposed coalesced weights) + masked partial BN1 stats
__global__ __launch_bounds__(256) void k_g1s(const float* __restrict__ xf,
    const float* __restrict__ w1t, const float* __restrict__ bias,
    const int* __restrict__ length, float* __restrict__ t1,
    float* __restrict__ gsum, float* __restrict__ gsq){
  int blk = blockIdx.x; int tid = threadIdx.x;
  int f = tid & 127, rh = tid >> 7;
  __shared__ float sx[8][128];
  __shared__ float red1[2][128], red2[2][128];
  int r0 = blk*8;
  for (int idx = tid; idx < 1024; idx += 256){
    int r = idx >> 7, m = idx & 127;
    sx[r][m] = xf[(r0+r)*128 + m];
  }
  __syncthreads();
  float bsv = bias[f];
  float s=0.f, s2=0.f;
  for (int rr = rh*4; rr < rh*4+4; rr++){
    int rg = r0 + rr; int b = rg >> 7, n = rg & 127;
    float acc = bsv;
    for (int m=0;m<128;m++) acc += sx[rr][m]*w1t[m*128+f];
    t1[rg*128+f] = acc;
    if (n < length[b]){ s += acc; s2 += acc*acc; }
  }
  red1[rh][f]=s; red2[rh][f]=s2; __syncthreads();
  if (tid < 128){
    atomicAdd(&gsum[tid], red1[0][tid]+red1[1][tid]);
    atomicAdd(&gsq[tid],  red2[0][tid]+red2[1][tid]);
  }
}

// finalize BN1 + relu + g2 GEMM (transposed) + partial BN2 stats
__global__ __launch_bounds__(256) void k_g2s(const float* __restrict__ t1,
    const float* __restrict__ gsum1, const float* __restrict__ gsq1,
    const float* __restrict__ g1, const float* __restrict__ bb1,
    const float* __restrict__ w2t, const float* __restrict__ bias2,
    const int* __restrict__ length, float* __restrict__ t2,
    float* __restrict__ gsum2, float* __restrict__ gsq2){
  int blk = blockIdx.x; int tid = threadIdx.x;
  int f = tid & 127, rh = tid >> 7;
  __shared__ float sy[8][128];
  __shared__ float red1[2][128], red2[2][128];
  int r0 = blk*8;
  float cnt = 0.f;
  for (int b=0;b<BB;b++) cnt += (float)length[b];
  float mu = gsum1[f]/cnt;
  float var = gsq1[f]/cnt - mu*mu;
  float istd = rsqrtf(fmaxf(var,0.0f)+EPSV);
  float gg = g1[f], bbv = bb1[f];
  for (int idx = tid; idx < 1024; idx += 256){
    int r = idx >> 7;
    float x = t1[(r0+r)*128 + f];
    float y = (x-mu)*istd*gg + bbv;
    sy[r][f] = fmaxf(y, 0.0f);
  }
  __syncthreads();
  float bsv = bias2[f];
  float s=0.f, s2=0.f;
  for (int rr = rh*4; rr < rh*4+4; rr++){
    int rg = r0 + rr; int b = rg >> 7, n = rg & 127;
    float acc = bsv;
    for (int m=0;m<128;m++) acc += sy[rr][m]*w2t[m*128+f];
    t2[rg*128+f] = acc;
    if (n < length[b]){ s += acc; s2 += acc*acc; }
  }
  red1[rh][f]=s; red2[rh][f]=s2; __syncthreads();
  if (tid < 128){
    atomicAdd(&gsum2[tid], red1[0][tid]+red1[1][tid]);
    atomicAdd(&gsq2[tid],  red2[0][tid]+red2[1][tid]);
  }
}

// final BN2-apply fused into pooling + linear head
__global__ void k_pool2(const float* __restrict__ xf, const float* __restrict__ t2,
                        const float* __restrict__ gsum2, const float* __restrict__ gsq2,
                        const float* __restrict__ g2, const float* __restrict__ bb2,
                        const int* __restrict__ length,
                        const float* lw, const float* lb, float* __restrict__ outp){
  int b = blockIdx.x, tid=threadIdx.x;
  int len = length[b];
  float cnt = 0.f;
  for (int q2=0;q2<BB;q2++) cnt += (float)length[q2];
  float mu = gsum2[tid]/cnt;
  float var = gsq2[tid]/cnt - mu*mu;
  float istd = rsqrtf(fmaxf(var,0.0f)+EPSV);
  float gg = g2[tid], bbv = bb2[tid];
  float s=0.f;
  for (int n2=0;n2<len;n2++){
    int o = (b*NN+n2)*HH+tid;
    float x = xf[o] + fmaxf((t2[o]-mu)*istd*gg+bbv, 0.0f);
    s += x;
  }
  s /= (float)len;
  __shared__ float red[128];
  red[tid]=s*lw[tid]; __syncthreads();
  for (int st=64;st>0;st>>=1){ if(tid<st) red[tid]+=red[tid+st]; __syncthreads(); }
  if (tid==0) outp[b]=red[0]+lb[0];
}

// ---------------- host ----------------

extern "C" void kernel_launch(void* const* d_in, const int* in_sizes, int n_in,
                              void* d_out, int out_size, void* d_ws, size_t ws_size,
                              hipStream_t stream) {
  (void)in_sizes; (void)n_in; (void)out_size; (void)ws_size;
  const float* e        = (const float*)d_in[0];
  const float* u        = (const float*)d_in[1];
  const float* atom_emb = (const float*)d_in[2];
  const float* bond_emb = (const float*)d_in[3];
  const float* eigw_W   = (const float*)d_in[4];
  const float* eigw_b   = (const float*)d_in[5];
  const float* mng      = (const float*)d_in[6];
  const float* mnb      = (const float*)d_in[7];
  const float* qkvW     = (const float*)d_in[8];
  const float* qkvb     = (const float*)d_in[9];
  const float* outW     = (const float*)d_in[10];
  const float* outb     = (const float*)d_in[11];
  const float* fng      = (const float*)d_in[12];
  const float* fnb      = (const float*)d_in[13];
  const float* ffn1W    = (const float*)d_in[14];
  const float* ffn1b    = (const float*)d_in[15];
  const float* ffn2W    = (const float*)d_in[16];
  const float* ffn2b    = (const float*)d_in[17];
  const float* decW     = (const float*)d_in[18];
  const float* decb     = (const float*)d_in[19];
  const float* fe1W     = (const float*)d_in[20];
  const float* fe1b     = (const float*)d_in[21];
  const float* fe2W     = (const float*)d_in[22];
  const float* fe2b     = (const float*)d_in[23];
  const float* preW     = (const float*)d_in[24];
  const float* preb     = (const float*)d_in[25];
  const float* f1W      = (const float*)d_in[26];
  const float* f1b      = (const float*)d_in[27];
  const float* bn1g     = (const float*)d_in[28];
  const float* bn1b     = (const float*)d_in[29];
  const float* f2W      = (const float*)d_in[30];
  const float* f2b      = (const float*)d_in[31];
  const float* bn2g     = (const float*)d_in[32];
  const float* bn2b     = (const float*)d_in[33];
  const float* linW     = (const float*)d_in[34];
  const float* linb     = (const float*)d_in[35];
  const int* nodef      = (const int*)d_in[36];
  const int* edgef      = (const int*)d_in[37];
  const int* length     = (const int*)d_in[38];

  float* outp = (float*)d_out;   // h[8] ++ new_e[4096] ++ attn[524288], f32

  char* p = (char*)d_ws;
  auto alloc = [&](size_t bytes)->void*{ void* r=(void*)p; p += (bytes+255)&~(size_t)255; return r; };
  const int TOK = BB*NN*HH;           // 131072
  float* eig   = (float*)alloc(TOK*4);
  float* q     = (float*)alloc(TOK*4);
  float* kT    = (float*)alloc(TOK*4);
  float* v     = (float*)alloc(TOK*4);
  float* attnf = (float*)alloc((size_t)BB*NHD*NN*NN*4);
  float* newe  = (float*)alloc(BB*NHD*NN*4);
  float* filt  = (float*)alloc((size_t)BB*NN*NN*4*4);
  bf16*  bases = (bf16*) alloc((size_t)BB*NN*NN*HH*2);
  float* xf0   = (float*)alloc(TOK*4);
  float* xfB   = (float*)alloc(TOK*4);
  float* xfC   = (float*)alloc(TOK*4);
  float* xfD   = (float*)alloc(TOK*4);
  float* t1    = (float*)alloc(TOK*4);
  float* t2    = (float*)alloc(TOK*4);
  float* xfW   = (float*)alloc(TOK*4);
  float* gs    = (float*)alloc(2048*4);
  ushortt* wbf = (ushortt*)alloc(81920*2);
  float* eigWT = (float*)alloc(16512*4);
  float* qkvWT = (float*)alloc(49152*4);
  float* outWT = (float*)alloc(16384*4);
  float* ffn1WT= (float*)alloc(16384*4);
  float* ffn2WT= (float*)alloc(16384*4);
  float* f1WT  = (float*)alloc(65536*4);
  float* f2WT  = (float*)alloc(65536*4);
  float* bondWall = (float*)alloc(5120*4);
  ushortt* Gbuf = (ushortt*)alloc((size_t)BB*NN*10*HH*2);   // 2.6 MB, L2-resident

  k_prep<<<512, 256, 0, stream>>>(fe2W, preW, eigw_W, qkvW, outW, ffn1W, ffn2W,
                                  f1W, f2W, atom_emb, nodef, bond_emb, preb,
                                  wbf, gs, xf0, eigWT, qkvWT, outWT, ffn1WT,
                                  ffn2WT, f1WT, f2WT, bondWall);

  // front end
  k_fe_a<<<BB*NN, 128, 0, stream>>>(e, eigWT, eigw_b, mng, mnb, qkvWT, qkvb, eig, q, kT, v);
  k_attn<<<BB*NHD*NN, 128, 0, stream>>>(q, kT, length, attnf, outp);
  k_fe_c<<<BB*NN, 128, 0, stream>>>(attnf, v, outWT, outb, fng, fnb,
                                    ffn1WT, ffn1b, ffn2WT, ffn2b, eig);
  k_dec<<<BB, 128, 0, stream>>>(eig, decW, decb, newe, outp);

  // bases
  k_filters<<<dim3(BB,8,8), dim3(16,16), 0, stream>>>(u, newe, filt);
  k_fe2<<<2*BB*NN, 256, 0, stream>>>(filt, fe1W, fe1b, wbf, fe2b, bases);

  // message passing: 5 kernels/layer
  const float* xfprev = xf0;
  float* xfcur = xfC;
  for (int l=0;l<LAY;l++){
    const ushortt* wbfl = wbf + 16384 + l*16384;
    float* gsl = gs + l*512;
    float* gsp = gs + (l-1)*512;
    k_xwl2<<<BB, 256, 0, stream>>>(xfprev, t2,
                                   (l>0)? gsp+256 : gs, (l>0)? gsp+384 : gs,
                                   bn2g + (l>0? (l-1)*HH:0), bn2b + (l>0? (l-1)*HH:0),
                                   length, (l>0)?1:0,
                                   wbfl, xfB, xfW);
    k_gel<<<BB*NN, 256, 0, stream>>>(xfW, bondWall + l*1280, Gbuf);
    const float* xin = (l==0)? xf0 : xfB;
    k_edge<<<BB*NN, 512, 0, stream>>>(xin, xfcur, bases, Gbuf, edgef, length);
    k_g1s<<<128, 256, 0, stream>>>(xfcur, f1WT + l*16384, f1b + l*HH, length,
                                   t1, gsl, gsl+128);
    k_g2s<<<128, 256, 0, stream>>>(t1, gsl, gsl+128, bn1g + l*HH, bn1b + l*HH,
                                   f2WT + l*16384, f2b + l*HH, length,
                                   t2, gsl+256, gsl+384);
    xfprev = xfcur;
    xfcur = (xfcur == xfC) ? xfD : xfC;
  }
  // final: BN2(layer3) applied inside pool (xfprev holds layer-3 output)
  k_pool2<<<BB, 128, 0, stream>>>(xfprev, t2, gs+3*512+256, gs+3*512+384,
                                  bn2g + 3*HH, bn2b + 3*HH, length, linW, linb, outp);
}

// Round 17
// 494.560 us; speedup vs baseline: 1.0351x; 1.0351x over previous
//
#include <hip/hip_runtime.h>
#include <hip/hip_bf16.h>
#include <math.h>

#define BB 8
#define NN 128
#define HH 128
#define NHD 4
#define DHD 32
#define LAY 4
#define EPSV 1e-5f

typedef __hip_bfloat16 bf16;
typedef unsigned short ushortt;
typedef short bf16x8 __attribute__((ext_vector_type(8)));
typedef float f32x4 __attribute__((ext_vector_type(4)));

__device__ __forceinline__ float b2f(bf16 x){ return __bfloat162float(x); }
__device__ __forceinline__ bf16 f2b(float x){ return __float2bfloat16(x); }
__device__ __forceinline__ float us2f(ushortt u){ return __uint_as_float(((unsigned)u)<<16); }
__device__ __forceinline__ ushortt f2us(float x){ bf16 b=__float2bfloat16(x); return *(ushortt*)&b; }
__device__ __forceinline__ float gelu_f(float x){ return 0.5f*x*(1.0f+erff(x*0.7071067811865476f)); }
// fast tanh-gelu — h-path serial loops only (k_edge); measured win there (r13)
__device__ __forceinline__ float gelu_h(float x){
  float t = 0.7978845608028654f*x*(1.0f + 0.044715f*x*x);
  float e = __expf(2.0f*t);
  float th = 1.0f - 2.0f/(e + 1.0f);
  return 0.5f*x*(1.0f + th);
}

// ---------------- prep: bf16 weights, transposes, bondW (all layers), xf init ----------------

__global__ __launch_bounds__(256) void k_prep(const float* __restrict__ fe2W,
    const float* __restrict__ preW, const float* __restrict__ eigW,
    const float* __restrict__ qkvW, const float* __restrict__ outW,
    const float* __restrict__ ffn1W, const float* __restrict__ ffn2W,
    const float* __restrict__ f1W, const float* __restrict__ f2W,
    const float* __restrict__ aemb, const int* __restrict__ nf,
    const float* __restrict__ bemb, const float* __restrict__ preb,
    ushortt* __restrict__ wbf, float* __restrict__ gs, float* __restrict__ xf0,
    float* __restrict__ eigWT, float* __restrict__ qkvWT, float* __restrict__ outWT,
    float* __restrict__ ffn1WT, float* __restrict__ ffn2WT,
    float* __restrict__ f1WT, float* __restrict__ f2WT,
    float* __restrict__ bondWall){
  int idx = blockIdx.x*256 + threadIdx.x;    // grid covers 131072
  if (idx < 2048) gs[idx] = 0.f;
  if (idx < 81920){
    float v = (idx < 16384) ? fe2W[idx] : preW[idx - 16384];
    wbf[idx] = f2us(v);
  }
  if (idx < 131072){
    int node = idx >> 7, h2 = idx & 127;
    xf0[idx] = aemb[nf[node]*HH + h2];
  }
  if (idx < 16512){ int o = idx/129, kq = idx - o*129; eigWT[kq*128+o] = eigW[idx]; }
  if (idx < 49152){ int o = idx>>7, m = idx&127; qkvWT[m*384+o] = qkvW[idx]; }
  if (idx < 16384){ int o = idx>>7, m = idx&127;
    outWT[m*128+o]  = outW[idx];
    ffn1WT[m*128+o] = ffn1W[idx];
    ffn2WT[m*128+o] = ffn2W[idx];
  }
  if (idx < 65536){ int l = idx>>14, r = idx&16383; int o = r>>7, m = r&127;
    f1WT[l*16384 + m*128+o] = f1W[idx];
    f2WT[l*16384 + m*128+o] = f2W[idx];
  }
  if (idx < 5120){   // bondW for all 4 layers: bond_emb @ preW[l]^T + preb[l]
    int l = idx / 1280; int r = idx - l*1280; int e2 = r >> 7; int hcol = r & 127;
    const float* br = bemb + e2*128;
    const float* wr = preW + l*16384 + hcol*128;
    float acc = preb[l*128 + hcol];
    for (int m=0;m<128;m++) acc += br[m]*wr[m];
    bondWall[idx] = acc;
  }
}

// ---------------- front end (all f32 — precision-critical for new_e) ----------------

__global__ void k_fe_a(const float* __restrict__ e, const float* __restrict__ eigWT,
                       const float* __restrict__ eigb, const float* __restrict__ g,
                       const float* __restrict__ bt, const float* __restrict__ qkvWT,
                       const float* __restrict__ qkvb,
                       float* __restrict__ eigout, float* __restrict__ q,
                       float* __restrict__ kT, float* __restrict__ v){
  int row = blockIdx.x; int tid = threadIdx.x;
  int b = row >> 7, n = row & 127;
  __shared__ float ee[129]; __shared__ float buf[128]; __shared__ float xm[128];
  float ev = e[row];
  if (tid < 64){
    float dv = expf(-0.1439115683121279f * (float)tid);
    float pe = ev * 100.0f * dv;
    ee[1+tid] = sinf(pe);
    ee[65+tid] = cosf(pe);
  }
  if (tid == 0) ee[0] = ev;
  __syncthreads();
  float x = eigb[tid];
  for (int k2=0;k2<129;k2++) x += ee[k2]*eigWT[k2*128+tid];
  eigout[row*HH+tid] = x;
  buf[tid]=x; __syncthreads();
  for (int s2=64;s2>0;s2>>=1){ if(tid<s2) buf[tid]+=buf[tid+s2]; __syncthreads(); }
  float mean = buf[0]*(1.0f/128.0f); __syncthreads();
  float d = x-mean; buf[tid]=d*d; __syncthreads();
  for (int s2=64;s2>0;s2>>=1){ if(tid<s2) buf[tid]+=buf[tid+s2]; __syncthreads(); }
  float var = buf[0]*(1.0f/128.0f);
  xm[tid] = d*rsqrtf(var+EPSV)*g[tid]+bt[tid];
  __syncthreads();
  #pragma unroll
  for (int s3=0;s3<3;s3++){
    float acc = qkvb[s3*HH+tid];
    const float* wt = qkvWT + s3*HH + tid;
    for (int m=0;m<HH;m++) acc += xm[m]*wt[m*384];
    if (s3==0) q[row*HH+tid]=acc;
    else if (s3==1) kT[b*16384 + tid*128 + n]=acc;
    else v[row*HH+tid]=acc;
  }
}

__global__ void k_attn(const float* __restrict__ q, const float* __restrict__ kT,
                       const int* __restrict__ length,
                       float* __restrict__ attnf, float* __restrict__ outp){
  int bx = blockIdx.x;
  int qi = bx & 127, hd = (bx>>7)&3, b = bx>>9;
  int tid = threadIdx.x;
  int len = length[b];
  __shared__ float qv[DHD]; __shared__ float red[128];
  if (tid < DHD) qv[tid] = q[(b*NN+qi)*HH + hd*DHD + tid];
  __syncthreads();
  float s = -1e30f;
  if (tid < len){
    const float* kr = kT + b*16384 + hd*DHD*128 + tid;
    float sc=0.f;
    for (int d2=0; d2<DHD; d2++) sc += qv[d2]*kr[d2*128];
    s = sc * 0.17677669529663687f;
  }
  red[tid]=s; __syncthreads();
  for (int st=64;st>0;st>>=1){ if(tid<st) red[tid]=fmaxf(red[tid],red[tid+st]); __syncthreads(); }
  float mx = red[0]; __syncthreads();
  float p = (tid<len)? expf(s-mx):0.0f;
  red[tid]=p; __syncthreads();
  for (int st=64;st>0;st>>=1){ if(tid<st) red[tid]+=red[tid+st]; __syncthreads(); }
  float a = p / red[0];
  int idx = ((b*NHD+hd)*NN+qi)*NN+tid;
  attnf[idx]=a;
  outp[4104 + idx]=a;
}

__global__ void k_fe_c(const float* __restrict__ attnf, const float* __restrict__ v,
                       const float* __restrict__ outWT, const float* __restrict__ outb,
                       const float* __restrict__ fng, const float* __restrict__ fnb,
                       const float* __restrict__ w1T, const float* __restrict__ b1,
                       const float* __restrict__ w2T, const float* __restrict__ b2,
                       float* __restrict__ eig){
  int row = blockIdx.x; int b = row>>7, qi = row&127;
  int tid = threadIdx.x;
  __shared__ float c[128]; __shared__ float buf[128]; __shared__ float xm[128]; __shared__ float tt[128];
  int hd = tid>>5;
  const float* ar = attnf + ((b*NHD+hd)*NN+qi)*NN;
  float acc=0.f;
  for (int j=0;j<NN;j++) acc += ar[j]*v[(b*NN+j)*HH+tid];
  c[tid]=acc; __syncthreads();
  float o = outb[tid];
  for (int m=0;m<HH;m++) o += c[m]*outWT[m*128+tid];
  float x = eig[row*HH+tid] + o;
  buf[tid]=x; __syncthreads();
  for (int s2=64;s2>0;s2>>=1){ if(tid<s2) buf[tid]+=buf[tid+s2]; __syncthreads(); }
  float mean=buf[0]*(1.f/128.f); __syncthreads();
  float d=x-mean; buf[tid]=d*d; __syncthreads();
  for (int s2=64;s2>0;s2>>=1){ if(tid<s2) buf[tid]+=buf[tid+s2]; __syncthreads(); }
  float var=buf[0]*(1.f/128.f);
  xm[tid]=d*rsqrtf(var+EPSV)*fng[tid]+fnb[tid];
  __syncthreads();
  float a1=b1[tid];
  for (int m=0;m<HH;m++) a1+=xm[m]*w1T[m*128+tid];
  tt[tid]=gelu_f(a1); __syncthreads();
  float a2=b2[tid];
  for (int m=0;m<HH;m++) a2+=tt[m]*w2T[m*128+tid];
  eig[row*HH+tid]=x+a2;
}

__global__ void k_dec(const float* __restrict__ eig, const float* dW, const float* db,
                      float* __restrict__ newe, float* __restrict__ outp){
  int b = blockIdx.x, n = threadIdx.x;
  __shared__ float w[NHD*HH];
  for (int i=n;i<NHD*HH;i+=128) w[i]=dW[i];
  __syncthreads();
  float acc[NHD];
  #pragma unroll
  for (int kk=0;kk<NHD;kk++) acc[kk]=db[kk];
  const float* er = eig + (b*NN+n)*HH;
  for (int h2=0;h2<HH;h2++){
    float ev = er[h2];
    #pragma unroll
    for (int kk=0;kk<NHD;kk++) acc[kk]+=ev*w[kk*HH+h2];
  }
  #pragma unroll
  for (int kk=0;kk<NHD;kk++){
    int idx=(b*NHD+kk)*NN+n; newe[idx]=acc[kk];
    outp[8 + idx]=acc[kk];
  }
}

// ---------------- bases ----------------

__global__ void k_filters(const float* __restrict__ u, const float* __restrict__ newe,
                          float* __restrict__ filt){
  int b = blockIdx.x, n0 = blockIdx.y*16, p0 = blockIdx.z*16;
  int tx = threadIdx.x, ty = threadIdx.y; int tid = ty*16+tx;
  __shared__ float un[16][17], upt[16][17], wk[4][16];
  float acc[4]={0.f,0.f,0.f,0.f};
  for (int mt=0; mt<8; mt++){
    __syncthreads();
    un[ty][tx]  = u[(b*NN+n0+ty)*NN + mt*16+tx];
    upt[tx][ty] = u[(b*NN+p0+ty)*NN + mt*16+tx];
    if (tid<64) wk[tid>>4][tid&15] = newe[(b*NHD+(tid>>4))*NN + mt*16 + (tid&15)];
    __syncthreads();
    #pragma unroll
    for (int mm=0;mm<16;mm++){
      float pr = un[ty][mm]*upt[mm][tx];
      #pragma unroll
      for (int kk=0;kk<4;kk++) acc[kk] += pr*wk[kk][mm];
    }
  }
  float4 o; o.x=acc[0];o.y=acc[1];o.z=acc[2];o.w=acc[3];
  *(float4*)&filt[((b*NN+n0+ty)*NN+p0+tx)*4] = o;
}

// bases: 2048 blocks (64 output rows each); exact gelu; coalesced stores
__global__ __launch_bounds__(256) void k_fe2(const float* __restrict__ filt,
    const float* __restrict__ w1g, const float* __restrict__ b1g,
    const ushortt* __restrict__ w2bf, const float* __restrict__ b2g,
    bf16* __restrict__ bases){
  int blk = blockIdx.x;
  int bi = blk >> 1;            // b*128 + n
  int r0 = (blk & 1)*64;
  int nloc = bi & 127;
  int tid = threadIdx.x;
  int lane = tid & 63, w = tid >> 6, quad = lane >> 4, l15 = lane & 15;
  __shared__ alignas(16) ushortt sT[64*132];
  __shared__ float w1[640], b1s[128], b2s[128];
  for (int i = tid; i < 640; i += 256) w1[i] = w1g[i];
  if (tid < 128){ b1s[tid] = b1g[tid]; b2s[tid] = b2g[tid]; }
  __syncthreads();
  int pr = r0 + w*16 + l15;                 // A row (m index) this lane feeds
  float4 f4 = ((const float4*)filt)[bi*128 + pr];
  float dg = (pr == nloc) ? 1.0f : 0.0f;
  f32x4 acc[8];
  #pragma unroll
  for (int nt=0;nt<8;nt++) acc[nt] = (f32x4){0.f,0.f,0.f,0.f};
  for (int kk = 0; kk < 128; kk += 32){
    bf16x8 af;
    #pragma unroll
    for (int j=0;j<8;j++){
      int m = kk + quad*8 + j;
      float a = b1s[m] + w1[m*5]*dg + w1[m*5+1]*f4.x + w1[m*5+2]*f4.y
              + w1[m*5+3]*f4.z + w1[m*5+4]*f4.w;
      af[j] = (short)f2us(gelu_f(a));
    }
    #pragma unroll
    for (int nt=0;nt<8;nt++){
      bf16x8 bfr = *(const bf16x8*)&w2bf[(nt*16+l15)*128 + kk + quad*8];
      acc[nt] = __builtin_amdgcn_mfma_f32_16x16x32_bf16(af, bfr, acc[nt], 0, 0, 0);
    }
  }
  #pragma unroll
  for (int nt=0;nt<8;nt++){
    int h = nt*16 + l15;
    float bb = b2s[h];
    #pragma unroll
    for (int reg=0;reg<4;reg++){
      int lr = w*16 + quad*4 + reg;
      sT[lr*132 + h] = f2us(gelu_f(acc[nt][reg] + bb));
    }
  }
  __syncthreads();
  ushort4* gout = (ushort4*)(bases + (size_t)bi*16384 + r0*128);
  for (int idx = tid; idx < 2048; idx += 256){
    int row = idx >> 5, seg = idx & 31;
    gout[idx] = *(const ushort4*)&sT[row*132 + seg*4];
  }
}

// ---------------- message passing ----------------

// per-layer (8 blocks): fused BN2-apply of previous layer; xfW = xfB @ preW^T (MFMA)
__global__ __launch_bounds__(256) void k_xwl2(const float* __restrict__ xfprev,
    const float* __restrict__ t2, const float* __restrict__ gsum2p,
    const float* __restrict__ gsq2p, const float* __restrict__ g2p,
    const float* __restrict__ bb2p, const int* __restrict__ length, int prevapply,
    const ushortt* __restrict__ wbfl, float* __restrict__ xfB,
    float* __restrict__ xfW){
  int b = blockIdx.x;
  int tid = threadIdx.x;
  int lane = tid & 63, w = tid >> 6, quad = lane >> 4, l15 = lane & 15;
  __shared__ alignas(16) ushortt sA[128*136];
  __shared__ float smu[128], sistd[128], sg[128], sbb[128];
  if (prevapply && tid < 128){
    float cnt = 0.f;
    for (int q2=0;q2<BB;q2++) cnt += (float)length[q2];
    float mu = gsum2p[tid]/cnt;
    float var = gsq2p[tid]/cnt - mu*mu;
    smu[tid]=mu; sistd[tid]=rsqrtf(fmaxf(var,0.0f)+EPSV);
    sg[tid]=g2p[tid]; sbb[tid]=bb2p[tid];
  }
  __syncthreads();
  for (int idx = tid; idx < 4096; idx += 256){
    int r = idx >> 5, c = idx & 31;
    float4 xv = ((const float4*)xfprev)[(b*128 + r)*32 + c];
    if (prevapply){
      float4 tv = ((const float4*)t2)[(b*128 + r)*32 + c];
      int f0 = c*4;
      xv.x += fmaxf((tv.x-smu[f0+0])*sistd[f0+0]*sg[f0+0]+sbb[f0+0], 0.f);
      xv.y += fmaxf((tv.y-smu[f0+1])*sistd[f0+1]*sg[f0+1]+sbb[f0+1], 0.f);
      xv.z += fmaxf((tv.z-smu[f0+2])*sistd[f0+2]*sg[f0+2]+sbb[f0+2], 0.f);
      xv.w += fmaxf((tv.w-smu[f0+3])*sistd[f0+3]*sg[f0+3]+sbb[f0+3], 0.f);
      ((float4*)xfB)[(b*128 + r)*32 + c] = xv;
    }
    ushort4 o;
    o.x=f2us(xv.x); o.y=f2us(xv.y); o.z=f2us(xv.z); o.w=f2us(xv.w);
    *(ushort4*)&sA[r*136 + c*4] = o;
  }
  __syncthreads();
  f32x4 acc[2][8];
  #pragma unroll
  for (int mt=0;mt<2;mt++)
    #pragma unroll
    for (int nt=0;nt<8;nt++) acc[mt][nt] = (f32x4){0.f,0.f,0.f,0.f};
  #pragma unroll
  for (int kk = 0; kk < 128; kk += 32){
    bf16x8 af[2], bfr[8];
    #pragma unroll
    for (int mt=0;mt<2;mt++) af[mt] = *(const bf16x8*)&sA[(w*32+mt*16+l15)*136 + kk + quad*8];
    #pragma unroll
    for (int nt=0;nt<8;nt++) bfr[nt] = *(const bf16x8*)&wbfl[(nt*16+l15)*128 + kk + quad*8];
    #pragma unroll
    for (int mt=0;mt<2;mt++)
      #pragma unroll
      for (int nt=0;nt<8;nt++)
        acc[mt][nt] = __builtin_amdgcn_mfma_f32_16x16x32_bf16(af[mt], bfr[nt], acc[mt][nt], 0, 0, 0);
  }
  #pragma unroll
  for (int mt=0;mt<2;mt++)
    #pragma unroll
    for (int nt=0;nt<8;nt++){
      int h = nt*16 + l15;
      #pragma unroll
      for (int reg=0;reg<4;reg++){
        int pr = w*32 + mt*16 + quad*4 + reg;
        xfW[(b*128 + pr)*128 + h] = acc[mt][nt][reg];
      }
    }
}

// per-edge elementwise (1024 blocks x 512 thr): gelu_h, 4-way i-striping, symmetric bases read
__global__ __launch_bounds__(512) void k_edge(const float* __restrict__ xfin, float* __restrict__ xfout,
    const bf16* __restrict__ bases, const float* __restrict__ xfW,
    const float* __restrict__ bondWl, const int* __restrict__ ef,
    const int* __restrict__ length){
  int bj = blockIdx.x; int b = bj >> 7, j = bj & 127;
  int len = length[b];
  int tid = threadIdx.x; int h = tid & 127, ih = tid >> 7;   // ih in 0..3
  __shared__ float sBW[10][128];
  __shared__ int sEf[128];
  __shared__ float part[4][128];
  for (int idx = tid; idx < 1280; idx += 512) sBW[idx>>7][idx&127] = bondWl[idx];
  if (tid < 128) sEf[tid] = ef[(b*NN + tid)*NN + j];
  __syncthreads();
  float agg = 0.f;
  if (j < len){
    const float* xwb = xfW + b*NN*HH + h;
    const bf16* bb = bases + ((size_t)b*NN + j)*NN*HH + h;
    for (int i = ih; i < len; i += 4){
      float vv = gelu_h(xwb[i*128] + sBW[sEf[i]][h]);
      agg += vv * b2f(bb[i*128]);
    }
  }
  part[ih][h] = agg; __syncthreads();
  if (tid < 128){
    int o = (b*NN + j)*HH + tid;
    xfout[o] = xfin[o] + part[0][tid] + part[1][tid] + part[2][tid] + part[3][tid];
  }
}

// g1 GEMM (transposed coalesced weights) + masked partial BN1 stats
__global__ __launch_bounds__(256) void k_g1s(const float* __restrict__ xf,
    const float* __restrict__ w1t, const float* __restrict__ bias,
    const int* __restrict__ length, float* __restrict__ t1,
    float* __restrict__ gsum, float* __restrict__ gsq){
  int blk = blockIdx.x; int tid = threadIdx.x;
  int f = tid & 127, rh = tid >> 7;
  __shared__ float sx[8][128];
  __shared__ float red1[2][128], red2[2][128];
  int r0 = blk*8;
  for (int idx = tid; idx < 1024; idx += 256){
    int r = idx >> 7, m = idx & 127;
    sx[r][m] = xf[(r0+r)*128 + m];
  }
  __syncthreads();
  float bsv = bias[f];
  float s=0.f, s2=0.f;
  for (int rr = rh*4; rr < rh*4+4; rr++){
    int rg = r0 + rr; int b = rg >> 7, n = rg & 127;
    float acc = bsv;
    for (int m=0;m<128;m++) acc += sx[rr][m]*w1t[m*128+f];
    t1[rg*128+f] = acc;
    if (n < length[b]){ s += acc; s2 += acc*acc; }
  }
  red1[rh][f]=s; red2[rh][f]=s2; __syncthreads();
  if (tid < 128){
    atomicAdd(&gsum[tid], red1[0][tid]+red1[1][tid]);
    atomicAdd(&gsq[tid],  red2[0][tid]+red2[1][tid]);
  }
}

// finalize BN1 + relu + g2 GEMM (transposed) + partial BN2 stats
__global__ __launch_bounds__(256) void k_g2s(const float* __restrict__ t1,
    const float* __restrict__ gsum1, const float* __restrict__ gsq1,
    const float* __restrict__ g1, const float* __restrict__ bb1,
    const float* __restrict__ w2t, const float* __restrict__ bias2,
    const int* __restrict__ length, float* __restrict__ t2,
    float* __restrict__ gsum2, float* __restrict__ gsq2){
  int blk = blockIdx.x; int tid = threadIdx.x;
  int f = tid & 127, rh = tid >> 7;
  __shared__ float sy[8][128];
  __shared__ float red1[2][128], red2[2][128];
  int r0 = blk*8;
  float cnt = 0.f;
  for (int b=0;b<BB;b++) cnt += (float)length[b];
  float mu = gsum1[f]/cnt;
  float var = gsq1[f]/cnt - mu*mu;
  float istd = rsqrtf(fmaxf(var,0.0f)+EPSV);
  float gg = g1[f], bbv = bb1[f];
  for (int idx = tid; idx < 1024; idx += 256){
    int r = idx >> 7;
    float x = t1[(r0+r)*128 + f];
    float y = (x-mu)*istd*gg + bbv;
    sy[r][f] = fmaxf(y, 0.0f);
  }
  __syncthreads();
  float bsv = bias2[f];
  float s=0.f, s2=0.f;
  for (int rr = rh*4; rr < rh*4+4; rr++){
    int rg = r0 + rr; int b = rg >> 7, n = rg & 127;
    float acc = bsv;
    for (int m=0;m<128;m++) acc += sy[rr][m]*w2t[m*128+f];
    t2[rg*128+f] = acc;
    if (n < length[b]){ s += acc; s2 += acc*acc; }
  }
  red1[rh][f]=s; red2[rh][f]=s2; __syncthreads();
  if (tid < 128){
    atomicAdd(&gsum2[tid], red1[0][tid]+red1[1][tid]);
    atomicAdd(&gsq2[tid],  red2[0][tid]+red2[1][tid]);
  }
}

// final BN2-apply fused into pooling + linear head
__global__ void k_pool2(const float* __restrict__ xf, const float* __restrict__ t2,
                        const float* __restrict__ gsum2, const float* __restrict__ gsq2,
                        const float* __restrict__ g2, const float* __restrict__ bb2,
                        const int* __restrict__ length,
                        const float* lw, const float* lb, float* __restrict__ outp){
  int b = blockIdx.x, tid=threadIdx.x;
  int len = length[b];
  float cnt = 0.f;
  for (int q2=0;q2<BB;q2++) cnt += (float)length[q2];
  float mu = gsum2[tid]/cnt;
  float var = gsq2[tid]/cnt - mu*mu;
  float istd = rsqrtf(fmaxf(var,0.0f)+EPSV);
  float gg = g2[tid], bbv = bb2[tid];
  float s=0.f;
  for (int n2=0;n2<len;n2++){
    int o = (b*NN+n2)*HH+tid;
    float x = xf[o] + fmaxf((t2[o]-mu)*istd*gg+bbv, 0.0f);
    s += x;
  }
  s /= (float)len;
  __shared__ float red[128];
  red[tid]=s*lw[tid]; __syncthreads();
  for (int st=64;st>0;st>>=1){ if(tid<st) red[tid]+=red[tid+st]; __syncthreads(); }
  if (tid==0) outp[b]=red[0]+lb[0];
}

// ---------------- host ----------------

extern "C" void kernel_launch(void* const* d_in, const int* in_sizes, int n_in,
                              void* d_out, int out_size, void* d_ws, size_t ws_size,
                              hipStream_t stream) {
  (void)in_sizes; (void)n_in; (void)out_size; (void)ws_size;
  const float* e        = (const float*)d_in[0];
  const float* u        = (const float*)d_in[1];
  const float* atom_emb = (const float*)d_in[2];
  const float* bond_emb = (const float*)d_in[3];
  const float* eigw_W   = (const float*)d_in[4];
  const float* eigw_b   = (const float*)d_in[5];
  const float* mng      = (const float*)d_in[6];
  const float* mnb      = (const float*)d_in[7];
  const float* qkvW     = (const float*)d_in[8];
  const float* qkvb     = (const float*)d_in[9];
  const float* outW     = (const float*)d_in[10];
  const float* outb     = (const float*)d_in[11];
  const float* fng      = (const float*)d_in[12];
  const float* fnb      = (const float*)d_in[13];
  const float* ffn1W    = (const float*)d_in[14];
  const float* ffn1b    = (const float*)d_in[15];
  const float* ffn2W    = (const float*)d_in[16];
  const float* ffn2b    = (const float*)d_in[17];
  const float* decW     = (const float*)d_in[18];
  const float* decb     = (const float*)d_in[19];
  const float* fe1W     = (const float*)d_in[20];
  const float* fe1b     = (const float*)d_in[21];
  const float* fe2W     = (const float*)d_in[22];
  const float* fe2b     = (const float*)d_in[23];
  const float* preW     = (const float*)d_in[24];
  const float* preb     = (const float*)d_in[25];
  const float* f1W      = (const float*)d_in[26];
  const float* f1b      = (const float*)d_in[27];
  const float* bn1g     = (const float*)d_in[28];
  const float* bn1b     = (const float*)d_in[29];
  const float* f2W      = (const float*)d_in[30];
  const float* f2b      = (const float*)d_in[31];
  const float* bn2g     = (const float*)d_in[32];
  const float* bn2b     = (const float*)d_in[33];
  const float* linW     = (const float*)d_in[34];
  const float* linb     = (const float*)d_in[35];
  const int* nodef      = (const int*)d_in[36];
  const int* edgef      = (const int*)d_in[37];
  const int* length     = (const int*)d_in[38];

  float* outp = (float*)d_out;   // h[8] ++ new_e[4096] ++ attn[524288], f32

  char* p = (char*)d_ws;
  auto alloc = [&](size_t bytes)->void*{ void* r=(void*)p; p += (bytes+255)&~(size_t)255; return r; };
  const int TOK = BB*NN*HH;           // 131072
  float* eig   = (float*)alloc(TOK*4);
  float* q     = (float*)alloc(TOK*4);
  float* kT    = (float*)alloc(TOK*4);
  float* v     = (float*)alloc(TOK*4);
  float* attnf = (float*)alloc((size_t)BB*NHD*NN*NN*4);
  float* newe  = (float*)alloc(BB*NHD*NN*4);
  float* filt  = (float*)alloc((size_t)BB*NN*NN*4*4);
  bf16*  bases = (bf16*) alloc((size_t)BB*NN*NN*HH*2);
  float* xf0   = (float*)alloc(TOK*4);
  float* xfB   = (float*)alloc(TOK*4);
  float* xfC   = (float*)alloc(TOK*4);
  float* xfD   = (float*)alloc(TOK*4);
  float* t1    = (float*)alloc(TOK*4);
  float* t2    = (float*)alloc(TOK*4);
  float* xfW   = (float*)alloc(TOK*4);
  float* gs    = (float*)alloc(2048*4);
  ushortt* wbf = (ushortt*)alloc(81920*2);
  float* eigWT = (float*)alloc(16512*4);
  float* qkvWT = (float*)alloc(49152*4);
  float* outWT = (float*)alloc(16384*4);
  float* ffn1WT= (float*)alloc(16384*4);
  float* ffn2WT= (float*)alloc(16384*4);
  float* f1WT  = (float*)alloc(65536*4);
  float* f2WT  = (float*)alloc(65536*4);
  float* bondWall = (float*)alloc(5120*4);

  k_prep<<<512, 256, 0, stream>>>(fe2W, preW, eigw_W, qkvW, outW, ffn1W, ffn2W,
                                  f1W, f2W, atom_emb, nodef, bond_emb, preb,
                                  wbf, gs, xf0, eigWT, qkvWT, outWT, ffn1WT,
                                  ffn2WT, f1WT, f2WT, bondWall);

  // front end
  k_fe_a<<<BB*NN, 128, 0, stream>>>(e, eigWT, eigw_b, mng, mnb, qkvWT, qkvb, eig, q, kT, v);
  k_attn<<<BB*NHD*NN, 128, 0, stream>>>(q, kT, length, attnf, outp);
  k_fe_c<<<BB*NN, 128, 0, stream>>>(attnf, v, outWT, outb, fng, fnb,
                                    ffn1WT, ffn1b, ffn2WT, ffn2b, eig);
  k_dec<<<BB, 128, 0, stream>>>(eig, decW, decb, newe, outp);

  // bases
  k_filters<<<dim3(BB,8,8), dim3(16,16), 0, stream>>>(u, newe, filt);
  k_fe2<<<2*BB*NN, 256, 0, stream>>>(filt, fe1W, fe1b, wbf, fe2b, bases);

  // message passing: 4 kernels/layer
  const float* xfprev = xf0;
  float* xfcur = xfC;
  for (int l=0;l<LAY;l++){
    const ushortt* wbfl = wbf + 16384 + l*16384;
    float* gsl = gs + l*512;
    float* gsp = gs + (l-1)*512;
    k_xwl2<<<BB, 256, 0, stream>>>(xfprev, t2,
                                   (l>0)? gsp+256 : gs, (l>0)? gsp+384 : gs,
                                   bn2g + (l>0? (l-1)*HH:0), bn2b + (l>0? (l-1)*HH:0),
                                   length, (l>0)?1:0,
                                   wbfl, xfB, xfW);
    const float* xin = (l==0)? xf0 : xfB;
    k_edge<<<BB*NN, 512, 0, stream>>>(xin, xfcur, bases, xfW, bondWall + l*1280,
                                      edgef, length);
    k_g1s<<<128, 256, 0, stream>>>(xfcur, f1WT + l*16384, f1b + l*HH, length,
                                   t1, gsl, gsl+128);
    k_g2s<<<128, 256, 0, stream>>>(t1, gsl, gsl+128, bn1g + l*HH, bn1b + l*HH,
                                   f2WT + l*16384, f2b + l*HH, length,
                                   t2, gsl+256, gsl+384);
    xfprev = xfcur;
    xfcur = (xfcur == xfC) ? xfD : xfC;
  }
  // final: BN2(layer3) applied inside pool (xfprev holds layer-3 output)
  k_pool2<<<BB, 128, 0, stream>>>(xfprev, t2, gs+3*512+256, gs+3*512+384,
                                  bn2g + 3*HH, bn2b + 3*HH, length, linW, linb, outp);
}